// Round 1
// baseline (681.559 us; speedup 1.0000x reference)
//
#include <hip/hip_runtime.h>
#include <math.h>

#define N_NODES   100000
#define N_FEAT    512
#define HIDDEN    16
#define N_CLASSES 7
#define N_EDGES   3200000

#define SCAN_CHUNK 1024
#define NB_SCAN ((N_NODES + SCAN_CHUNK - 1) / SCAN_CHUNK)  // 98

// ---------- CSR build ----------

__global__ void k_zero(int* __restrict__ counts) {
    int i = blockIdx.x * 256 + threadIdx.x;
    if (i < N_NODES) counts[i] = 0;
}

__global__ void k_count(const int* __restrict__ dst, int* __restrict__ counts) {
    int e = blockIdx.x * 256 + threadIdx.x;
    if (e < N_EDGES) atomicAdd(&counts[dst[e]], 1);
}

__global__ void k_partial(const int* __restrict__ counts, int* __restrict__ bsum) {
    __shared__ int sd[256];
    int t = threadIdx.x;
    int base = blockIdx.x * SCAN_CHUNK + t * 4;
    int s = 0;
#pragma unroll
    for (int k = 0; k < 4; k++) {
        int idx = base + k;
        if (idx < N_NODES) s += counts[idx];
    }
    sd[t] = s;
    __syncthreads();
    for (int off = 128; off > 0; off >>= 1) {
        if (t < off) sd[t] += sd[t + off];
        __syncthreads();
    }
    if (t == 0) bsum[blockIdx.x] = sd[0];
}

__global__ void k_scan_small(int* __restrict__ bsum) {
    __shared__ int sd[128];
    int t = threadIdx.x;
    int v = (t < NB_SCAN) ? bsum[t] : 0;
    sd[t] = v;
    __syncthreads();
    for (int off = 1; off < 128; off <<= 1) {
        int add = (t >= off) ? sd[t - off] : 0;
        __syncthreads();
        sd[t] += add;
        __syncthreads();
    }
    if (t < NB_SCAN) bsum[t] = sd[t] - v;  // exclusive
}

__global__ void k_scan_final(const int* __restrict__ counts, const int* __restrict__ bsum,
                             int* __restrict__ rowptr, float* __restrict__ dinv,
                             int* __restrict__ cursor) {
    __shared__ int sd[256];
    int t = threadIdx.x;
    int base = blockIdx.x * SCAN_CHUNK + t * 4;
    int c[4];
    int s = 0;
#pragma unroll
    for (int k = 0; k < 4; k++) {
        int idx = base + k;
        c[k] = (idx < N_NODES) ? counts[idx] : 0;
        s += c[k];
    }
    sd[t] = s;
    __syncthreads();
    for (int off = 1; off < 256; off <<= 1) {
        int add = (t >= off) ? sd[t - off] : 0;
        __syncthreads();
        sd[t] += add;
        __syncthreads();
    }
    int p = sd[t] - s + bsum[blockIdx.x];
#pragma unroll
    for (int k = 0; k < 4; k++) {
        int idx = base + k;
        if (idx < N_NODES) {
            rowptr[idx] = p;
            dinv[idx]   = rsqrtf((float)(c[k] + 1));  // deg = in-deg + self-loop
            cursor[idx] = 0;
        }
        p += c[k];
    }
}

__global__ void k_fill(const int* __restrict__ src, const int* __restrict__ dst,
                       const int* __restrict__ rowptr, int* __restrict__ cursor,
                       int* __restrict__ csr) {
    int e = blockIdx.x * 256 + threadIdx.x;
    if (e < N_EDGES) {
        int d = dst[e];
        int pos = rowptr[d] + atomicAdd(&cursor[d], 1);
        csr[pos] = src[e];
    }
}

// ---------- GEMM1: hs1 = dinv ⊙ (x @ W1), 16 lanes per row ----------

__global__ __launch_bounds__(256) void k_gemm1(const float* __restrict__ x,
                                               const float* __restrict__ W1,
                                               const float* __restrict__ dinv,
                                               float* __restrict__ hs1) {
    __shared__ float wl[512 * 17];  // pitch 17 breaks bank-conflict stride
    int tid = threadIdx.x;
    for (int idx = tid; idx < N_FEAT * HIDDEN; idx += 256) {
        int col = idx >> 4, o = idx & 15;
        wl[col * 17 + o] = W1[idx];
    }
    __syncthreads();

    int lane = tid & 15;
    int row  = blockIdx.x * 16 + (tid >> 4);
    const float4* xr = (const float4*)(x + (size_t)row * N_FEAT);

    float acc[16];
#pragma unroll
    for (int o = 0; o < 16; o++) acc[o] = 0.f;

#pragma unroll
    for (int i = 0; i < 8; i++) {
        int col = i * 64 + lane * 4;
        float4 xv = xr[col >> 2];
#pragma unroll
        for (int j = 0; j < 4; j++) {
            float xj = (&xv.x)[j];
            const float* wr = &wl[(col + j) * 17];
#pragma unroll
            for (int o = 0; o < 16; o++) acc[o] += xj * wr[o];
        }
    }

    // reduce the 16-lane group
#pragma unroll
    for (int m = 1; m < 16; m <<= 1) {
#pragma unroll
        for (int o = 0; o < 16; o++) acc[o] += __shfl_xor(acc[o], m, 64);
    }

    if (lane == 0) {
        float dn = dinv[row];
        float4* outp = (float4*)(hs1 + (size_t)row * 16);
        outp[0] = make_float4(acc[0] * dn, acc[1] * dn, acc[2] * dn, acc[3] * dn);
        outp[1] = make_float4(acc[4] * dn, acc[5] * dn, acc[6] * dn, acc[7] * dn);
        outp[2] = make_float4(acc[8] * dn, acc[9] * dn, acc[10] * dn, acc[11] * dn);
        outp[3] = make_float4(acc[12] * dn, acc[13] * dn, acc[14] * dn, acc[15] * dn);
    }
}

// ---------- agg1 + bias + relu + GEMM2 fused: hs2 = dinv ⊙ (relu(agg(hs1)+b1) @ W2) ----------

__global__ __launch_bounds__(256) void k_agg1(const float* __restrict__ hs1,
                                              const int* __restrict__ rowptr,
                                              const int* __restrict__ counts,
                                              const int* __restrict__ csr,
                                              const float* __restrict__ dinv,
                                              const float* __restrict__ b1,
                                              const float* __restrict__ W2,
                                              float* __restrict__ hs2) {
    __shared__ float w2l[HIDDEN * N_CLASSES];
    int tid = threadIdx.x;
    if (tid < HIDDEN * N_CLASSES) w2l[tid] = W2[tid];
    __syncthreads();

    int lane = tid & 15;
    int n = blockIdx.x * 16 + (tid >> 4);
    int cnt = counts[n];
    const int* sp = csr + rowptr[n];

    float acc = hs1[(size_t)n * 16 + lane];  // self-loop term
    int e = 0;
    for (; e + 4 <= cnt; e += 4) {
        int s0 = sp[e], s1 = sp[e + 1], s2 = sp[e + 2], s3 = sp[e + 3];
        float a0 = hs1[(size_t)s0 * 16 + lane];
        float a1 = hs1[(size_t)s1 * 16 + lane];
        float a2 = hs1[(size_t)s2 * 16 + lane];
        float a3 = hs1[(size_t)s3 * 16 + lane];
        acc += a0 + a1 + a2 + a3;
    }
    for (; e < cnt; e++) acc += hs1[(size_t)sp[e] * 16 + lane];

    float z = fmaxf(dinv[n] * acc + b1[lane], 0.f);

    float t[7];
#pragma unroll
    for (int j = 0; j < 7; j++) t[j] = z * w2l[lane * 7 + j];
#pragma unroll
    for (int m = 1; m < 16; m <<= 1) {
#pragma unroll
        for (int j = 0; j < 7; j++) t[j] += __shfl_xor(t[j], m, 64);
    }

    if (lane == 0) {
        float dn = dinv[n];
        float4* o = (float4*)(hs2 + (size_t)n * 8);
        o[0] = make_float4(dn * t[0], dn * t[1], dn * t[2], dn * t[3]);
        o[1] = make_float4(dn * t[4], dn * t[5], dn * t[6], 0.f);
    }
}

// ---------- agg2 + bias + log_softmax: out = log_softmax(dinv*(agg(hs2)) + b2) ----------

__global__ __launch_bounds__(256) void k_agg2(const float* __restrict__ hs2,
                                              const int* __restrict__ rowptr,
                                              const int* __restrict__ counts,
                                              const int* __restrict__ csr,
                                              const float* __restrict__ dinv,
                                              const float* __restrict__ b2,
                                              float* __restrict__ out) {
    int tid = threadIdx.x;
    int lane = tid & 7;
    int n = blockIdx.x * 32 + (tid >> 3);
    int cnt = counts[n];
    const int* sp = csr + rowptr[n];

    float acc = hs2[(size_t)n * 8 + lane];  // self-loop
    int e = 0;
    for (; e + 4 <= cnt; e += 4) {
        int s0 = sp[e], s1 = sp[e + 1], s2 = sp[e + 2], s3 = sp[e + 3];
        acc += hs2[(size_t)s0 * 8 + lane] + hs2[(size_t)s1 * 8 + lane] +
               hs2[(size_t)s2 * 8 + lane] + hs2[(size_t)s3 * 8 + lane];
    }
    for (; e < cnt; e++) acc += hs2[(size_t)sp[e] * 8 + lane];

    float v = dinv[n] * acc + ((lane < 7) ? b2[lane] : -3.4e38f);

    float m = v;
#pragma unroll
    for (int mk = 1; mk < 8; mk <<= 1) m = fmaxf(m, __shfl_xor(m, mk, 64));
    float ex = expf(v - m);
    float s = ex;
#pragma unroll
    for (int mk = 1; mk < 8; mk <<= 1) s += __shfl_xor(s, mk, 64);

    if (lane < 7) out[(size_t)n * 7 + lane] = v - m - logf(s);
}

// ---------- launch ----------

extern "C" void kernel_launch(void* const* d_in, const int* in_sizes, int n_in,
                              void* d_out, int out_size, void* d_ws, size_t ws_size,
                              hipStream_t stream) {
    const float* x  = (const float*)d_in[0];
    const int*   ei = (const int*)d_in[1];
    const float* W1 = (const float*)d_in[2];
    const float* b1 = (const float*)d_in[3];
    const float* W2 = (const float*)d_in[4];
    const float* b2 = (const float*)d_in[5];
    float* out = (float*)d_out;

    const int* src = ei;
    const int* dst = ei + N_EDGES;

    char* w = (char*)d_ws;
    int*   counts = (int*)(w + 0);          // 400000 B
    int*   cursor = (int*)(w + 400128);     // 400000 B
    int*   rowptr = (int*)(w + 800256);     // 400000 B
    int*   bsum   = (int*)(w + 1200640);    // 512 B
    float* dinv   = (float*)(w + 1201152);  // 400000 B
    float* hs1    = (float*)(w + 1601280);  // 6.4 MB
    float* hs2    = (float*)(w + 8001280);  // 3.2 MB
    int*   csr    = (int*)(w + 11201280);   // 12.8 MB  (total ~24 MB)

    k_zero<<<(N_NODES + 255) / 256, 256, 0, stream>>>(counts);
    k_count<<<(N_EDGES + 255) / 256, 256, 0, stream>>>(dst, counts);
    k_partial<<<NB_SCAN, 256, 0, stream>>>(counts, bsum);
    k_scan_small<<<1, 128, 0, stream>>>(bsum);
    k_scan_final<<<NB_SCAN, 256, 0, stream>>>(counts, bsum, rowptr, dinv, cursor);
    k_fill<<<(N_EDGES + 255) / 256, 256, 0, stream>>>(src, dst, rowptr, cursor, csr);
    k_gemm1<<<N_NODES / 16, 256, 0, stream>>>(x, W1, dinv, hs1);
    k_agg1<<<N_NODES / 16, 256, 0, stream>>>(hs1, rowptr, counts, csr, dinv, b1, W2, hs2);
    k_agg2<<<N_NODES / 32, 256, 0, stream>>>(hs2, rowptr, counts, csr, dinv, b2, out);
}